// Round 4
// baseline (67.069 us; speedup 1.0000x reference)
//
#include <hip/hip_runtime.h>
#include <stdint.h>

typedef __attribute__((ext_vector_type(8))) short     bf16x8;
typedef __attribute__((ext_vector_type(4))) float     f32x4;
typedef __attribute__((ext_vector_type(4))) float     float4v;
typedef __attribute__((ext_vector_type(2))) unsigned  uint2v;
typedef __attribute__((ext_vector_type(4))) unsigned  uint4v;

#define DEVINL static __device__ __forceinline__

#define B_  2
#define H_  8
#define S_  2048
#define D_  64
#define KVB 128
#define NKT (S_ / KVB)

DEVINL unsigned short f2bf(float f) {
  union { float f; unsigned u; } v; v.f = f;
  unsigned r = v.u + 0x7FFFu + ((v.u >> 16) & 1u);   // RNE
  return (unsigned short)(r >> 16);
}

// ---------------- prep: build MFMA-fragment-ordered bf16 K and V ----------------
// Kf[b][kt][mt][s][lane][j] = bf16( K[b][kt*128 + mt*16 + (lane&15)][s*32 + (lane>>4)*8 + j] )
// Vf[b][kt][s][nt][lane][j] = bf16( V[b][kt*128 + s*32 + (lane>>4)*8 + j][nt*16 + (lane&15)] )
__global__ __launch_bounds__(256) void prep_kernel(
    const float* __restrict__ K, const float* __restrict__ V,
    unsigned short* __restrict__ Kf, unsigned short* __restrict__ Vf) {
  const int t = threadIdx.x;
  if (blockIdx.x < 128) {
    // ---- Kf: one thread per 8 consecutive d of one key (32B coalesced read) ----
    const int gt  = blockIdx.x * 256 + t;       // 0..32767
    const int b   = gt >> 14;
    const int key = (gt >> 3) & 2047;           // within-b key index
    const int d0  = gt & 7;                     // d-chunk (8 floats)
    const int kt  = key >> 7;
    const int mt  = (key >> 4) & 7;
    const int ql  = key & 15;
    const int s   = d0 >> 2;
    const int g   = d0 & 3;
    const int lane = g * 16 + ql;

    const float* src = K + ((size_t)(b * 2048 + key)) * 64 + d0 * 8;
    const float4v x0 = *(const float4v*)(src);
    const float4v x1 = *(const float4v*)(src + 4);
    uint4v o;
    o.x = (unsigned)f2bf(x0.x) | ((unsigned)f2bf(x0.y) << 16);
    o.y = (unsigned)f2bf(x0.z) | ((unsigned)f2bf(x0.w) << 16);
    o.z = (unsigned)f2bf(x1.x) | ((unsigned)f2bf(x1.y) << 16);
    o.w = (unsigned)f2bf(x1.z) | ((unsigned)f2bf(x1.w) << 16);
    const size_t off = ((size_t)((((b * 16 + kt) * 8 + mt) * 2 + s)) * 64 + lane) * 8;
    *(uint4v*)(Kf + off) = o;
  } else {
    // ---- Vf: per block (b, kt, s): transpose 32 keys x 64 d through LDS ----
    __shared__ float Vs[32][65];
    const int vb = blockIdx.x - 128;            // 0..127
    const int b  = vb >> 6;
    const int kt = (vb >> 2) & 15;
    const int s  = vb & 3;

    const int r  = t >> 3;                      // key row 0..31
    const int c0 = (t & 7) * 8;                 // d col
    const float* src = V + ((size_t)(b * 2048 + kt * 128 + s * 32 + r)) * 64 + c0;
    const float4v y0 = *(const float4v*)(src);
    const float4v y1 = *(const float4v*)(src + 4);
    Vs[r][c0 + 0] = y0.x; Vs[r][c0 + 1] = y0.y; Vs[r][c0 + 2] = y0.z; Vs[r][c0 + 3] = y0.w;
    Vs[r][c0 + 4] = y1.x; Vs[r][c0 + 5] = y1.y; Vs[r][c0 + 6] = y1.z; Vs[r][c0 + 7] = y1.w;
    __syncthreads();

    const int nt   = t >> 6;                    // 0..3
    const int lane = t & 63;
    const int g    = lane >> 4;
    const int ql   = lane & 15;
    unsigned short o[8];
#pragma unroll
    for (int j = 0; j < 8; ++j) o[j] = f2bf(Vs[g * 8 + j][nt * 16 + ql]);
    uint4v w;
    w.x = (unsigned)o[0] | ((unsigned)o[1] << 16);
    w.y = (unsigned)o[2] | ((unsigned)o[3] << 16);
    w.z = (unsigned)o[4] | ((unsigned)o[5] << 16);
    w.w = (unsigned)o[6] | ((unsigned)o[7] << 16);
    const size_t off = ((size_t)((((b * 16 + kt) * 4 + s)) * 4 + nt) * 64 + lane) * 8;
    *(uint4v*)(Vf + off) = w;
  }
}

// ---------------- main attention kernel: no K/V LDS, no barriers ----------------
__global__ __launch_bounds__(256, 2) void attn_kernel(
    const float* __restrict__ Q, const unsigned short* __restrict__ Kf,
    const unsigned short* __restrict__ Vf, float* __restrict__ O) {
  // LDS: only per-wave P [16 q][128 keys], XOR-swizzled chunks
  __shared__ __align__(16) unsigned short Plds[4][2048];

  const int bid = blockIdx.x;
  const int b  = bid >> 8;
  const int h  = (bid >> 5) & 7;
  const int qt = bid & 31;

  const int tid  = threadIdx.x;
  const int lane = tid & 63;
  const int wave = tid >> 6;
  const int g    = lane >> 4;       // 0..3
  const int ql   = lane & 15;       // 0..15
  const int qx   = ql & 7;
  const int gh   = g >> 1;
  const int glo  = g & 1;

  const unsigned short* Kb = Kf + (size_t)b * (NKT * 8 * 2 * 512);
  const unsigned short* Vb = Vf + (size_t)b * (NKT * 4 * 4 * 512);

  // ---- Q fragments (scaled by 1/sqrt(D) * log2(e)) ----
  const float qscale = 0.125f * 1.4426950408889634f;
  const float* qrow = Q + ((size_t)((b * H_ + h) * S_) + (size_t)(qt * 64 + wave * 16 + ql)) * 64;
  bf16x8 qfrag[2];
#pragma unroll
  for (int s = 0; s < 2; ++s) {
    const float* p = qrow + s * 32 + g * 8;
    float4v x0 = *(const float4v*)(p);
    float4v x1 = *(const float4v*)(p + 4);
    bf16x8 f;
    f[0] = (short)f2bf(x0.x * qscale); f[1] = (short)f2bf(x0.y * qscale);
    f[2] = (short)f2bf(x0.z * qscale); f[3] = (short)f2bf(x0.w * qscale);
    f[4] = (short)f2bf(x1.x * qscale); f[5] = (short)f2bf(x1.y * qscale);
    f[6] = (short)f2bf(x1.z * qscale); f[7] = (short)f2bf(x1.w * qscale);
    qfrag[s] = f;
  }

  // ones fragment for the l-sum MFMA
  bf16x8 ones;
#pragma unroll
  for (int j = 0; j < 8; ++j) ones[j] = (short)0x3F80;

  f32x4 acc[4];
#pragma unroll
  for (int nt = 0; nt < 4; ++nt) acc[nt] = (f32x4){0.f, 0.f, 0.f, 0.f};
  f32x4 acc5 = (f32x4){0.f, 0.f, 0.f, 0.f};
  float mrun = -__builtin_inff();

  for (int kt = 0; kt < NKT; ++kt) {
    const unsigned short* Kt = Kb + (size_t)kt * 8192;   // 8 mt x 2 s x 512
    const unsigned short* Vt = Vb + (size_t)kt * 8192;   // 4 s x 4 nt x 512

    // ---- QK^T (swapped): sc[mt] rows = keys mt*16+4g+r, cols = q = ql ----
    f32x4 sc[8];
#pragma unroll
    for (int mt = 0; mt < 8; ++mt) sc[mt] = (f32x4){0.f, 0.f, 0.f, 0.f};
    __builtin_amdgcn_s_setprio(1);
#pragma unroll
    for (int s = 0; s < 2; ++s) {
#pragma unroll
      for (int mt = 0; mt < 8; ++mt) {
        const bf16x8 a = *(const bf16x8*)(Kt + (mt * 2 + s) * 512 + lane * 8);
        sc[mt] = __builtin_amdgcn_mfma_f32_16x16x32_bf16(a, qfrag[s], sc[mt], 0, 0, 0);
      }
    }
    __builtin_amdgcn_s_setprio(0);

    // ---- per-q row max over 32 local values, reduce across g groups ----
    float mx = fmaxf(fmaxf(sc[0][0], sc[0][1]), fmaxf(sc[0][2], sc[0][3]));
#pragma unroll
    for (int mt = 1; mt < 8; ++mt) {
      const float m0 = fmaxf(fmaxf(sc[mt][0], sc[mt][1]), fmaxf(sc[mt][2], sc[mt][3]));
      mx = fmaxf(mx, m0);
    }
    mx = fmaxf(mx, __shfl_xor(mx, 16));
    mx = fmaxf(mx, __shfl_xor(mx, 32));

    // ---- defer-max (T13) ----
    if (!__all(mx <= mrun + 8.f)) {
      const float mnew = fmaxf(mrun, mx);
      const float fac  = __builtin_amdgcn_exp2f(mrun - mnew);
      float facr[4];
#pragma unroll
      for (int r = 0; r < 4; ++r) facr[r] = __shfl(fac, g * 4 + r);
#pragma unroll
      for (int nt = 0; nt < 4; ++nt)
#pragma unroll
        for (int r = 0; r < 4; ++r) acc[nt][r] *= facr[r];
#pragma unroll
      for (int r = 0; r < 4; ++r) acc5[r] *= facr[r];
      mrun = mnew;
    }

    // ---- P = exp2(sc - mrun), pack bf16, write swizzled per-wave LDS ----
#pragma unroll
    for (int mt = 0; mt < 8; ++mt) {
      const float p0 = __builtin_amdgcn_exp2f(sc[mt][0] - mrun);
      const float p1 = __builtin_amdgcn_exp2f(sc[mt][1] - mrun);
      const float p2 = __builtin_amdgcn_exp2f(sc[mt][2] - mrun);
      const float p3 = __builtin_amdgcn_exp2f(sc[mt][3] - mrun);
      uint2v w;
      w.x = (unsigned)f2bf(p0) | ((unsigned)f2bf(p1) << 16);
      w.y = (unsigned)f2bf(p2) | ((unsigned)f2bf(p3) << 16);
      *(uint2v*)&Plds[wave][ql * 128 + ((2 * mt + gh) ^ qx) * 8 + 4 * glo] = w;
    }
    asm volatile("" ::: "memory");   // P writes ordered before PV reads (TBAA insurance)

    // ---- PV + l-sum ----
    __builtin_amdgcn_s_setprio(1);
#pragma unroll
    for (int s = 0; s < 4; ++s) {
      const bf16x8 pa = *(const bf16x8*)&Plds[wave][ql * 128 + ((s * 4 + g) ^ qx) * 8];
      acc5 = __builtin_amdgcn_mfma_f32_16x16x32_bf16(pa, ones, acc5, 0, 0, 0);
#pragma unroll
      for (int nt = 0; nt < 4; ++nt) {
        const bf16x8 bv = *(const bf16x8*)(Vt + (s * 4 + nt) * 512 + lane * 8);
        acc[nt] = __builtin_amdgcn_mfma_f32_16x16x32_bf16(pa, bv, acc[nt], 0, 0, 0);
      }
    }
    __builtin_amdgcn_s_setprio(0);
  }

  // ---- epilogue ----
  float inv[4];
#pragma unroll
  for (int r = 0; r < 4; ++r) inv[r] = 1.f / acc5[r];
  float* obase = O + ((size_t)((b * H_ + h) * S_) + (size_t)(qt * 64 + wave * 16)) * 64;
#pragma unroll
  for (int nt = 0; nt < 4; ++nt)
#pragma unroll
    for (int r = 0; r < 4; ++r)
      obase[(size_t)(4 * g + r) * 64 + nt * 16 + ql] = acc[nt][r] * inv[r];
}

extern "C" void kernel_launch(void* const* d_in, const int* in_sizes, int n_in,
                              void* d_out, int out_size, void* d_ws, size_t ws_size,
                              hipStream_t stream) {
  const float* Q = (const float*)d_in[0];
  const float* K = (const float*)d_in[1];
  const float* V = (const float*)d_in[2];
  float* O = (float*)d_out;

  unsigned short* Kf = (unsigned short*)d_ws;                       // 512 KiB
  unsigned short* Vf = Kf + (size_t)B_ * NKT * 8 * 2 * 512;         // 512 KiB

  prep_kernel<<<256, 256, 0, stream>>>(K, V, Kf, Vf);
  attn_kernel<<<B_ * H_ * (S_ / 64), 256, 0, stream>>>(Q, Kf, Vf, O);
}

// Round 5
// 47.096 us; speedup vs baseline: 1.4241x; 1.4241x over previous
//
#include <hip/hip_runtime.h>
#include <stdint.h>

typedef __attribute__((ext_vector_type(8)))  short    bf16x8;
typedef __attribute__((ext_vector_type(16))) float    f32x16;
typedef __attribute__((ext_vector_type(4)))  float    float4v;
typedef __attribute__((ext_vector_type(4)))  unsigned uint4v;

#define DEVINL static __device__ __forceinline__

#define B_  2
#define H_  8
#define S_  2048
#define D_  64
#define KVB 128
#define NKT (S_ / KVB)

DEVINL unsigned short f2bf(float f) {
  union { float f; unsigned u; } v; v.f = f;
  unsigned r = v.u + 0x7FFFu + ((v.u >> 16) & 1u);   // RNE
  return (unsigned short)(r >> 16);
}

DEVINL unsigned pk2(float a, float b) {
  return (unsigned)f2bf(a) | ((unsigned)f2bf(b) << 16);
}

DEVINL void gload_lds16(const void* g, void* l) {
  __builtin_amdgcn_global_load_lds(
      (const __attribute__((address_space(1))) void*)g,
      (__attribute__((address_space(3))) void*)l, 16, 0, 0);
}

DEVINL bf16x8 frag_from_words(unsigned a, unsigned b, unsigned c, unsigned d) {
  union { unsigned u[4]; bf16x8 v; } x;
  x.u[0] = a; x.u[1] = b; x.u[2] = c; x.u[3] = d;
  return x.v;
}

// C-row map for 32x32 MFMA: row = (r&3) + 8*(r>>2) + 4*hi
#define CROW(r, hi) (((r) & 3) + 8 * ((r) >> 2) + 4 * (hi))

// ---------------- prep (R3-proven): K bf16 [b][key][d]; V bf16 transposed [b][d][s] ----------------
__global__ __launch_bounds__(256) void prep_kernel(
    const float* __restrict__ K, const float* __restrict__ V,
    unsigned short* __restrict__ Kb, unsigned short* __restrict__ Vt) {
  const int t = threadIdx.x;
  if (blockIdx.x < 128) {
    const int base = blockIdx.x * 2048 + t * 8;
    const float4v a = *(const float4v*)(K + base);
    const float4v b = *(const float4v*)(K + base + 4);
    uint4v o;
    o.x = (unsigned)f2bf(a.x) | ((unsigned)f2bf(a.y) << 16);
    o.y = (unsigned)f2bf(a.z) | ((unsigned)f2bf(a.w) << 16);
    o.z = (unsigned)f2bf(b.x) | ((unsigned)f2bf(b.y) << 16);
    o.w = (unsigned)f2bf(b.z) | ((unsigned)f2bf(b.w) << 16);
    *(uint4v*)(Kb + base) = o;
  } else {
    __shared__ float Vf[64][65];
    const int vb   = blockIdx.x - 128;
    const int b    = vb >> 5;
    const int sblk = vb & 31;
    const int r = t >> 2, c = t & 3;
    const float* src = V + ((size_t)(b * S_ + sblk * 64 + r)) * 64 + c * 16;
#pragma unroll
    for (int j = 0; j < 4; ++j) {
      float4v x = *(const float4v*)(src + 4 * j);
      Vf[r][c * 16 + 4 * j + 0] = x.x;
      Vf[r][c * 16 + 4 * j + 1] = x.y;
      Vf[r][c * 16 + 4 * j + 2] = x.z;
      Vf[r][c * 16 + 4 * j + 3] = x.w;
    }
    __syncthreads();
    unsigned short o[16];
#pragma unroll
    for (int j = 0; j < 16; ++j) o[j] = f2bf(Vf[c * 16 + j][r]);
    unsigned short* dst = Vt + ((size_t)(b * 64 + r)) * S_ + sblk * 64 + c * 16;
    uint4v w0, w1;
    w0.x = (unsigned)o[0]  | ((unsigned)o[1]  << 16);
    w0.y = (unsigned)o[2]  | ((unsigned)o[3]  << 16);
    w0.z = (unsigned)o[4]  | ((unsigned)o[5]  << 16);
    w0.w = (unsigned)o[6]  | ((unsigned)o[7]  << 16);
    w1.x = (unsigned)o[8]  | ((unsigned)o[9]  << 16);
    w1.y = (unsigned)o[10] | ((unsigned)o[11] << 16);
    w1.z = (unsigned)o[12] | ((unsigned)o[13] << 16);
    w1.w = (unsigned)o[14] | ((unsigned)o[15] << 16);
    *(uint4v*)(dst)     = w0;
    *(uint4v*)(dst + 8) = w1;
  }
}

// ---------------- attention: 32x32 MFMA, key-split waves, P in registers ----------------
__global__ __launch_bounds__(256, 2) void attn_kernel(
    const float* __restrict__ Q, const unsigned short* __restrict__ Kb,
    const unsigned short* __restrict__ Vt, float* __restrict__ O) {
  // smem: [0,16K)=K buf0, [16K,32K)=K buf1, [32K,48K)=V buf0, [48K,64K)=V buf1
  // K buf: [128 key][64 d] bf16, 128B rows, 8 chunks, chunk ^= key&7
  // V buf: [64 d][128 key] bf16, 256B rows, 16 chunks, low3(chunk) ^= d&7
  __shared__ __align__(16) unsigned char smem[65536];

  const int bid = blockIdx.x;
  const int b  = bid >> 8;
  const int h  = (bid >> 5) & 7;
  const int qt = bid & 31;

  const int tid  = threadIdx.x;
  const int lane = tid & 63;
  const int wave = tid >> 6;
  const int qg   = wave & 1;        // q-group (32 rows each)
  const int kh   = wave >> 1;       // key-half (64 keys each)
  const int hi   = lane >> 5;       // 0..1
  const int lq   = lane & 31;       // q (B cols) / key (A rows) / d (V cols)
  const int l7   = lane & 7;

  const unsigned short* Kbase = Kb + (size_t)b * (S_ * 64);
  const unsigned short* Vbase = Vt + (size_t)b * (64 * S_);

  // ---- Q B-fragments: qfrag[ks] elem j = Q[qrow][ks*16 + hi*8 + j] * scale ----
  const float qscale = 0.125f * 1.4426950408889634f;
  const float* qrow = Q + ((size_t)((b * H_ + h) * S_) + (size_t)(qt * 64 + qg * 32 + lq)) * 64;
  bf16x8 qfrag[4];
#pragma unroll
  for (int ks = 0; ks < 4; ++ks) {
    const float* p = qrow + ks * 16 + hi * 8;
    float4v x0 = *(const float4v*)(p);
    float4v x1 = *(const float4v*)(p + 4);
    bf16x8 f;
    f[0] = (short)f2bf(x0.x * qscale); f[1] = (short)f2bf(x0.y * qscale);
    f[2] = (short)f2bf(x0.z * qscale); f[3] = (short)f2bf(x0.w * qscale);
    f[4] = (short)f2bf(x1.x * qscale); f[5] = (short)f2bf(x1.y * qscale);
    f[6] = (short)f2bf(x1.z * qscale); f[7] = (short)f2bf(x1.w * qscale);
    qfrag[ks] = f;
  }

  // staging lane constants (linear LDS dest, inverse-XOR global source)
  const int krow   = lane >> 3;                  // 0..7  (K: 8 rows / gload)
  const int kchunk = (lane & 7) ^ krow;          // K source chunk
  const int vrow   = lane >> 4;                  // 0..3  (V: 4 rows / gload)

  f32x16 acc0, acc1;
#pragma unroll
  for (int r = 0; r < 16; ++r) { acc0[r] = 0.f; acc1[r] = 0.f; }
  float mrun = -__builtin_inff();
  float lrun = 0.f;

#define KL(BUF) ((unsigned short*)(smem + (BUF) * 16384))
#define VL(BUF) ((unsigned short*)(smem + 32768 + (BUF) * 16384))

#define STAGE(BUF, KT)                                                                   \
  do {                                                                                   \
    _Pragma("unroll")                                                                    \
    for (int i = 0; i < 4; ++i) {                                                        \
      const int kj = wave * 4 + i;               /* K seg: rows 8kj..8kj+7 */            \
      gload_lds16(Kbase + (size_t)((KT) * KVB + kj * 8 + krow) * 64 + kchunk * 8,        \
                  KL(BUF) + kj * 512 + lane * 8);                                        \
      const int vj = wave * 4 + i;               /* V seg: d rows 4vj..4vj+3 */          \
      const int vr = vj * 4 + vrow;                                                      \
      const int vch = (lane & 15) ^ (vr & 7);                                            \
      gload_lds16(Vbase + (size_t)vr * S_ + (KT) * KVB + vch * 8,                        \
                  VL(BUF) + vj * 512 + lane * 8);                                        \
    }                                                                                    \
  } while (0)

  STAGE(0, 0);

  int buf = 0;
  for (int kt = 0; kt < NKT; ++kt) {
    __syncthreads();   // tile kt staged; everyone done reading buf^1

    if (kt + 1 < NKT) STAGE(buf ^ 1, kt + 1);

    // ---- QK^T (swapped, 32x32x16): c0/c1 = scores^T for key-tiles kh*64+{0,32} ----
    f32x16 c0, c1;
#pragma unroll
    for (int r = 0; r < 16; ++r) { c0[r] = 0.f; c1[r] = 0.f; }
    const unsigned short* Kt = KL(buf);
    __builtin_amdgcn_s_setprio(1);
#pragma unroll
    for (int ks = 0; ks < 4; ++ks) {
      const int ch = (2 * ks + hi) ^ l7;
      const bf16x8 a0 = *(const bf16x8*)(Kt + (kh * 64 + lq) * 64 + ch * 8);
      c0 = __builtin_amdgcn_mfma_f32_32x32x16_bf16(a0, qfrag[ks], c0, 0, 0, 0);
      const bf16x8 a1 = *(const bf16x8*)(Kt + (kh * 64 + 32 + lq) * 64 + ch * 8);
      c1 = __builtin_amdgcn_mfma_f32_32x32x16_bf16(a1, qfrag[ks], c1, 0, 0, 0);
    }
    __builtin_amdgcn_s_setprio(0);

    // ---- row max for q=lq over this wave's 64 keys ----
    float mx = fmaxf(c0[0], c0[1]);
#pragma unroll
    for (int r = 2; r < 16; ++r) mx = fmaxf(mx, c0[r]);
#pragma unroll
    for (int r = 0; r < 16; ++r) mx = fmaxf(mx, c1[r]);
    mx = fmaxf(mx, __shfl_xor(mx, 32));

    // ---- defer-max (T13, log2 domain, THR=8) ----
    if (!__all(mx <= mrun + 8.f)) {
      const float mnew = fmaxf(mrun, mx);
      const float fac  = __builtin_amdgcn_exp2f(mrun - mnew);
#pragma unroll
      for (int r = 0; r < 16; ++r) {
        const float fr = __shfl(fac, CROW(r, hi));
        acc0[r] *= fr; acc1[r] *= fr;
      }
      lrun *= fac;
      mrun = mnew;
    }

    // ---- P = exp2(sc - mrun) in place; l-sum ----
    float psum = 0.f;
#pragma unroll
    for (int r = 0; r < 16; ++r) {
      c0[r] = __builtin_amdgcn_exp2f(c0[r] - mrun);
      c1[r] = __builtin_amdgcn_exp2f(c1[r] - mrun);
      psum += c0[r] + c1[r];
    }
    psum += __shfl_xor(psum, 32);
    lrun += psum;

    // ---- PV: assemble P A-frags in-register (shfl_xor 32), MFMA against V ----
    const unsigned short* Vb = VL(buf);
#pragma unroll
    for (int ks = 0; ks < 4; ++ks) {
      const int e = ks & 1;
      const f32x16 ct = (ks >> 1) ? c1 : c0;
      const unsigned wx0 = pk2(ct[8 * e + 0], ct[8 * e + 1]);
      const unsigned wx1 = pk2(ct[8 * e + 2], ct[8 * e + 3]);
      const unsigned wy0 = pk2(ct[8 * e + 4], ct[8 * e + 5]);
      const unsigned wy1 = pk2(ct[8 * e + 6], ct[8 * e + 7]);
      const unsigned s0 = hi ? wx0 : wy0;
      const unsigned s1 = hi ? wx1 : wy1;
      const unsigned r0 = (unsigned)__shfl_xor((int)s0, 32);
      const unsigned r1 = (unsigned)__shfl_xor((int)s1, 32);
      const bf16x8 pfrag = frag_from_words(hi ? r0 : wx0, hi ? r1 : wx1,
                                           hi ? wy0 : r0, hi ? wy1 : r1);
      const int ch = (kh * 8) | ((2 * ks + hi) ^ l7);
      __builtin_amdgcn_s_setprio(1);
      const bf16x8 bv0 = *(const bf16x8*)(Vb + (size_t)lq * 128 + ch * 8);
      acc0 = __builtin_amdgcn_mfma_f32_32x32x16_bf16(pfrag, bv0, acc0, 0, 0, 0);
      const bf16x8 bv1 = *(const bf16x8*)(Vb + (size_t)(32 + lq) * 128 + ch * 8);
      acc1 = __builtin_amdgcn_mfma_f32_32x32x16_bf16(pfrag, bv1, acc1, 0, 0, 0);
      __builtin_amdgcn_s_setprio(0);
    }

    buf ^= 1;
  }

  // ---- cross-key-half combine via LDS, then normalize & store (wave kh=0) ----
  __syncthreads();                                   // K/V LDS free now
  float* Mbuf = (float*)(smem + 16384);              // [2 qg][2 kh][32]
  float* Lbuf = (float*)(smem + 16384 + 512);        // [2 qg][2 kh][32]
  float* Abuf = (float*)(smem + 32768);              // [2 qg][32][64]
  if (lane < 32) {
    Mbuf[(qg * 2 + kh) * 32 + lane] = mrun;
    Lbuf[(qg * 2 + kh) * 32 + lane] = lrun;
  }
  __syncthreads();
  const float mo = Mbuf[(qg * 2 + (kh ^ 1)) * 32 + lq];
  const float lo = Lbuf[(qg * 2 + (kh ^ 1)) * 32 + lq];
  const float mtot  = fmaxf(mrun, mo);
  const float sself = __builtin_amdgcn_exp2f(mrun - mtot);
  const float ltot  = lrun * sself + lo * __builtin_amdgcn_exp2f(mo - mtot);

  if (kh == 1) {
#pragma unroll
    for (int r = 0; r < 16; ++r) {
      const float sr = __shfl(sself, CROW(r, hi));
      Abuf[qg * 2048 + CROW(r, hi) * 64 + lq]      = acc0[r] * sr;
      Abuf[qg * 2048 + CROW(r, hi) * 64 + 32 + lq] = acc1[r] * sr;
    }
  }
  __syncthreads();
  if (kh == 0) {
    const float linv = 1.f / ltot;
    float* obase = O + ((size_t)((b * H_ + h) * S_) + (size_t)(qt * 64 + qg * 32)) * 64;
#pragma unroll
    for (int r = 0; r < 16; ++r) {
      const float sr = __shfl(sself, CROW(r, hi));
      const float iv = __shfl(linv,  CROW(r, hi));
      const int row  = CROW(r, hi);
      obase[(size_t)row * 64 + lq]      = (acc0[r] * sr + Abuf[qg * 2048 + row * 64 + lq]) * iv;
      obase[(size_t)row * 64 + 32 + lq] = (acc1[r] * sr + Abuf[qg * 2048 + row * 64 + 32 + lq]) * iv;
    }
  }
}

extern "C" void kernel_launch(void* const* d_in, const int* in_sizes, int n_in,
                              void* d_out, int out_size, void* d_ws, size_t ws_size,
                              hipStream_t stream) {
  const float* Q = (const float*)d_in[0];
  const float* K = (const float*)d_in[1];
  const float* V = (const float*)d_in[2];
  float* O = (float*)d_out;

  unsigned short* Kb = (unsigned short*)d_ws;
  unsigned short* Vt = Kb + (size_t)B_ * S_ * 64;

  prep_kernel<<<192, 256, 0, stream>>>(K, V, Kb, Vt);
  attn_kernel<<<B_ * H_ * (S_ / 64), 256, 0, stream>>>(Q, Kb, Vt, O);
}

// Round 6
// 42.378 us; speedup vs baseline: 1.5827x; 1.1113x over previous
//
#include <hip/hip_runtime.h>
#include <hip/hip_bf16.h>
#include <stdint.h>

typedef __attribute__((ext_vector_type(8)))  short    bf16x8;
typedef __attribute__((ext_vector_type(16))) float    f32x16;
typedef __attribute__((ext_vector_type(2)))  float    f32x2;
typedef __attribute__((ext_vector_type(4)))  float    float4v;
typedef __attribute__((ext_vector_type(4)))  unsigned uint4v;
typedef __attribute__((ext_vector_type(2)))  int      int2v;

#define DEVINL static __device__ __forceinline__

#define B_  2
#define H_  8
#define S_  2048
#define D_  64
#define KVB 128
#define NKT (S_ / KVB)

DEVINL unsigned short f2bf(float f) {
  union { float f; unsigned u; } v; v.f = f;
  unsigned r = v.u + 0x7FFFu + ((v.u >> 16) & 1u);   // RNE
  return (unsigned short)(r >> 16);
}

DEVINL unsigned short bfu(float f) {                  // compiler-visible conversion
  __hip_bfloat16 h = __float2bfloat16(f);
  unsigned short u; __builtin_memcpy(&u, &h, 2); return u;
}

DEVINL unsigned pkcvt(float a, float b) {
  return (unsigned)bfu(a) | ((unsigned)bfu(b) << 16);
}

DEVINL void gload_lds16(const void* g, void* l) {
  __builtin_amdgcn_global_load_lds(
      (const __attribute__((address_space(1))) void*)g,
      (__attribute__((address_space(3))) void*)l, 16, 0, 0);
}

DEVINL bf16x8 frag_from_words(unsigned a, unsigned b, unsigned c, unsigned d) {
  union { unsigned u[4]; bf16x8 v; } x;
  x.u[0] = a; x.u[1] = b; x.u[2] = c; x.u[3] = d;
  return x.v;
}

// C-row map for 32x32 MFMA: row = (r&3) + 8*(r>>2) + 4*hi
#define CROW(r, hi) (((r) & 3) + 8 * ((r) >> 2) + 4 * (hi))

// ---------------- prep (proven): K bf16 [b][key][d]; V bf16 transposed [b][d][s] ----------------
__global__ __launch_bounds__(256) void prep_kernel(
    const float* __restrict__ K, const float* __restrict__ V,
    unsigned short* __restrict__ Kb, unsigned short* __restrict__ Vt) {
  const int t = threadIdx.x;
  if (blockIdx.x < 128) {
    const int base = blockIdx.x * 2048 + t * 8;
    const float4v a = *(const float4v*)(K + base);
    const float4v b = *(const float4v*)(K + base + 4);
    uint4v o;
    o.x = (unsigned)f2bf(a.x) | ((unsigned)f2bf(a.y) << 16);
    o.y = (unsigned)f2bf(a.z) | ((unsigned)f2bf(a.w) << 16);
    o.z = (unsigned)f2bf(b.x) | ((unsigned)f2bf(b.y) << 16);
    o.w = (unsigned)f2bf(b.z) | ((unsigned)f2bf(b.w) << 16);
    *(uint4v*)(Kb + base) = o;
  } else {
    __shared__ float Vf[64][65];
    const int vb   = blockIdx.x - 128;
    const int b    = vb >> 5;
    const int sblk = vb & 31;
    const int r = t >> 2, c = t & 3;
    const float* src = V + ((size_t)(b * S_ + sblk * 64 + r)) * 64 + c * 16;
#pragma unroll
    for (int j = 0; j < 4; ++j) {
      float4v x = *(const float4v*)(src + 4 * j);
      Vf[r][c * 16 + 4 * j + 0] = x.x;
      Vf[r][c * 16 + 4 * j + 1] = x.y;
      Vf[r][c * 16 + 4 * j + 2] = x.z;
      Vf[r][c * 16 + 4 * j + 3] = x.w;
    }
    __syncthreads();
    unsigned short o[16];
#pragma unroll
    for (int j = 0; j < 16; ++j) o[j] = f2bf(Vf[c * 16 + j][r]);
    unsigned short* dst = Vt + ((size_t)(b * 64 + r)) * S_ + sblk * 64 + c * 16;
    uint4v w0, w1;
    w0.x = (unsigned)o[0]  | ((unsigned)o[1]  << 16);
    w0.y = (unsigned)o[2]  | ((unsigned)o[3]  << 16);
    w0.z = (unsigned)o[4]  | ((unsigned)o[5]  << 16);
    w0.w = (unsigned)o[6]  | ((unsigned)o[7]  << 16);
    w1.x = (unsigned)o[8]  | ((unsigned)o[9]  << 16);
    w1.y = (unsigned)o[10] | ((unsigned)o[11] << 16);
    w1.z = (unsigned)o[12] | ((unsigned)o[13] << 16);
    w1.w = (unsigned)o[14] | ((unsigned)o[15] << 16);
    *(uint4v*)(dst)     = w0;
    *(uint4v*)(dst + 8) = w1;
  }
}

// ---------------- attention: 32x32 MFMA, key-split waves, P in registers ----------------
__global__ __launch_bounds__(256, 2) void attn_kernel(
    const float* __restrict__ Q, const unsigned short* __restrict__ Kb,
    const unsigned short* __restrict__ Vt, float* __restrict__ O) {
  // smem: [0,16K)=K buf0, [16K,32K)=K buf1, [32K,48K)=V buf0, [48K,64K)=V buf1
  // K buf: [128 key][64 d] bf16, 128B rows, 8 chunks, chunk ^= key&7
  // V buf: [64 d][128 key] bf16, 256B rows, 16 chunks, low3(chunk) ^= d&7
  __shared__ __align__(16) unsigned char smem[65536];

  const int bid = blockIdx.x;
  const int b  = bid >> 8;
  const int h  = (bid >> 5) & 7;
  const int qt = bid & 31;

  const int tid  = threadIdx.x;
  const int lane = tid & 63;
  const int wave = tid >> 6;
  const int qg   = wave & 1;        // q-group (32 rows each)
  const int kh   = wave >> 1;       // key-half (64 keys each)
  const int hi   = lane >> 5;       // 0..1
  const int lq   = lane & 31;       // q (B cols) / key (A rows) / d (V cols)
  const int l7   = lane & 7;

  const unsigned short* Kbase = Kb + (size_t)b * (S_ * 64);
  const unsigned short* Vbase = Vt + (size_t)b * (64 * S_);

  // ---- Q B-fragments: qfrag[ks] elem j = Q[qrow][ks*16 + hi*8 + j] * scale ----
  const float qscale = 0.125f * 1.4426950408889634f;
  const float* qrow = Q + ((size_t)((b * H_ + h) * S_) + (size_t)(qt * 64 + qg * 32 + lq)) * 64;
  bf16x8 qfrag[4];
#pragma unroll
  for (int ks = 0; ks < 4; ++ks) {
    const float* p = qrow + ks * 16 + hi * 8;
    float4v x0 = *(const float4v*)(p);
    float4v x1 = *(const float4v*)(p + 4);
    bf16x8 f;
    f[0] = (short)f2bf(x0.x * qscale); f[1] = (short)f2bf(x0.y * qscale);
    f[2] = (short)f2bf(x0.z * qscale); f[3] = (short)f2bf(x0.w * qscale);
    f[4] = (short)f2bf(x1.x * qscale); f[5] = (short)f2bf(x1.y * qscale);
    f[6] = (short)f2bf(x1.z * qscale); f[7] = (short)f2bf(x1.w * qscale);
    qfrag[ks] = f;
  }

  // staging lane constants (linear LDS dest, inverse-XOR global source)
  const int krow = lane >> 3;                  // 0..7  (K: 8 rows / gload)
  const int kch  = (lane & 7) ^ krow;          // K source chunk
  const int vrow = lane >> 4;                  // 0..3  (V: 4 rows / gload)
  const int vb0  = (lane & 15) ^ vrow;         // V source chunk, i even

  // running global source pointers (advance per tile; strips per-iter addr math)
  const unsigned short* kp  = Kbase + (size_t)(wave * 32 + krow) * 64 + kch * 8;
  const unsigned short* vpA = Vbase + (size_t)(wave * 16 + vrow) * S_ + vb0 * 8;
  const unsigned short* vpB = Vbase + (size_t)(wave * 16 + vrow) * S_ + (vb0 ^ 4) * 8;

  f32x16 acc0, acc1;
#pragma unroll
  for (int r = 0; r < 16; ++r) { acc0[r] = 0.f; acc1[r] = 0.f; }
  float mrun = -__builtin_inff();
  float lrun = 0.f;

#define STAGE(BUF)                                                                       \
  do {                                                                                   \
    _Pragma("unroll")                                                                    \
    for (int i = 0; i < 4; ++i) {                                                        \
      gload_lds16(kp + i * 512,                                                          \
                  smem + (BUF) * 16384 + (wave * 4 + i) * 1024 + lane * 16);             \
      gload_lds16(((i & 1) ? vpB : vpA) + i * 8192,                                      \
                  smem + 32768 + (BUF) * 16384 + (wave * 4 + i) * 1024 + lane * 16);     \
    }                                                                                    \
    kp += 8192; vpA += KVB; vpB += KVB;                                                  \
  } while (0)

  STAGE(0);

  int buf = 0;
  for (int kt = 0; kt < NKT; ++kt) {
    __syncthreads();   // tile kt staged; everyone done reading buf^1

    if (kt + 1 < NKT) STAGE(buf ^ 1);

    // ---- QK^T (swapped, 32x32x16): c0/c1 = scores^T for key-tiles kh*64+{0,32} ----
    f32x16 c0, c1;
#pragma unroll
    for (int r = 0; r < 16; ++r) { c0[r] = 0.f; c1[r] = 0.f; }
    const unsigned short* Kt = (const unsigned short*)(smem + buf * 16384);
    __builtin_amdgcn_s_setprio(1);
#pragma unroll
    for (int ks = 0; ks < 4; ++ks) {
      const int ch = (2 * ks + hi) ^ l7;
      const bf16x8 a0 = *(const bf16x8*)(Kt + (kh * 64 + lq) * 64 + ch * 8);
      c0 = __builtin_amdgcn_mfma_f32_32x32x16_bf16(a0, qfrag[ks], c0, 0, 0, 0);
      const bf16x8 a1 = *(const bf16x8*)(Kt + (kh * 64 + 32 + lq) * 64 + ch * 8);
      c1 = __builtin_amdgcn_mfma_f32_32x32x16_bf16(a1, qfrag[ks], c1, 0, 0, 0);
    }
    __builtin_amdgcn_s_setprio(0);

    // ---- row max via packed f32 (v_pk_max), then cross-half ----
    f32x2 m2 = (f32x2){c0[0], c0[1]};
#pragma unroll
    for (int r = 1; r < 8; ++r)
      m2 = __builtin_elementwise_max(m2, (f32x2){c0[2 * r], c0[2 * r + 1]});
#pragma unroll
    for (int r = 0; r < 8; ++r)
      m2 = __builtin_elementwise_max(m2, (f32x2){c1[2 * r], c1[2 * r + 1]});
    float mx = fmaxf(m2.x, m2.y);
    mx = fmaxf(mx, __shfl_xor(mx, 32));

    // ---- defer-max (T13, log2 domain, THR=8) ----
    if (!__all(mx <= mrun + 8.f)) {
      const float mnew = fmaxf(mrun, mx);
      const float fac  = __builtin_amdgcn_exp2f(mrun - mnew);
#pragma unroll
      for (int r = 0; r < 16; ++r) {
        const float fr = __shfl(fac, CROW(r, hi));
        acc0[r] *= fr; acc1[r] *= fr;
      }
      lrun *= fac;
      mrun = mnew;
    }

    // ---- P = exp2(sc - mrun) in place; packed l-sum ----
#pragma unroll
    for (int r = 0; r < 16; ++r) {
      c0[r] = __builtin_amdgcn_exp2f(c0[r] - mrun);
      c1[r] = __builtin_amdgcn_exp2f(c1[r] - mrun);
    }
    f32x2 ps = (f32x2){0.f, 0.f};
#pragma unroll
    for (int r = 0; r < 8; ++r) {
      ps += (f32x2){c0[2 * r], c0[2 * r + 1]};
      ps += (f32x2){c1[2 * r], c1[2 * r + 1]};
    }
    float psum = ps.x + ps.y;
    psum += __shfl_xor(psum, 32);
    lrun += psum;

    // ---- PV: P A-frags via permlane32_swap (T12), MFMA against V ----
    const unsigned short* Vb = (const unsigned short*)(smem + 32768 + buf * 16384);
#pragma unroll
    for (int ks = 0; ks < 4; ++ks) {
      const int e = ks & 1;
      const f32x16 ct = (ks >> 1) ? c1 : c0;
      const unsigned wx0 = pkcvt(ct[8 * e + 0], ct[8 * e + 1]);
      const unsigned wx1 = pkcvt(ct[8 * e + 2], ct[8 * e + 3]);
      const unsigned wy0 = pkcvt(ct[8 * e + 4], ct[8 * e + 5]);
      const unsigned wy1 = pkcvt(ct[8 * e + 6], ct[8 * e + 7]);
      // (word0, word2) = swap(wx0, wy0); (word1, word3) = swap(wx1, wy1)
      const int2v s02 = __builtin_amdgcn_permlane32_swap((int)wx0, (int)wy0, false, false);
      const int2v s13 = __builtin_amdgcn_permlane32_swap((int)wx1, (int)wy1, false, false);
      const bf16x8 pfrag = frag_from_words((unsigned)s02.x, (unsigned)s13.x,
                                           (unsigned)s02.y, (unsigned)s13.y);
      const int ch = (kh * 8) | ((2 * ks + hi) ^ l7);
      __builtin_amdgcn_s_setprio(1);
      const bf16x8 bv0 = *(const bf16x8*)(Vb + (size_t)lq * 128 + ch * 8);
      acc0 = __builtin_amdgcn_mfma_f32_32x32x16_bf16(pfrag, bv0, acc0, 0, 0, 0);
      const bf16x8 bv1 = *(const bf16x8*)(Vb + (size_t)(32 + lq) * 128 + ch * 8);
      acc1 = __builtin_amdgcn_mfma_f32_32x32x16_bf16(pfrag, bv1, acc1, 0, 0, 0);
      __builtin_amdgcn_s_setprio(0);
    }

    buf ^= 1;
  }

  // ---- cross-key-half combine via LDS, then normalize & store (wave kh=0) ----
  __syncthreads();                                   // K/V LDS free now
  float* Mbuf = (float*)(smem + 16384);              // [2 qg][2 kh][32]
  float* Lbuf = (float*)(smem + 16384 + 512);        // [2 qg][2 kh][32]
  float* Abuf = (float*)(smem + 32768);              // [2 qg][32][64]
  if (lane < 32) {
    Mbuf[(qg * 2 + kh) * 32 + lane] = mrun;
    Lbuf[(qg * 2 + kh) * 32 + lane] = lrun;
  }
  __syncthreads();
  const float mo = Mbuf[(qg * 2 + (kh ^ 1)) * 32 + lq];
  const float lo = Lbuf[(qg * 2 + (kh ^ 1)) * 32 + lq];
  const float mtot  = fmaxf(mrun, mo);
  const float sself = __builtin_amdgcn_exp2f(mrun - mtot);
  const float ltot  = lrun * sself + lo * __builtin_amdgcn_exp2f(mo - mtot);

  if (kh == 1) {
#pragma unroll
    for (int r = 0; r < 16; ++r) {
      const float sr = __shfl(sself, CROW(r, hi));
      Abuf[qg * 2048 + CROW(r, hi) * 64 + lq]      = acc0[r] * sr;
      Abuf[qg * 2048 + CROW(r, hi) * 64 + 32 + lq] = acc1[r] * sr;
    }
  }
  __syncthreads();
  if (kh == 0) {
    const float linv = 1.f / ltot;
    float* obase = O + ((size_t)((b * H_ + h) * S_) + (size_t)(qt * 64 + qg * 32)) * 64;
#pragma unroll
    for (int r = 0; r < 16; ++r) {
      const float sr = __shfl(sself, CROW(r, hi));
      const float iv = __shfl(linv,  CROW(r, hi));
      const int row  = CROW(r, hi);
      obase[(size_t)row * 64 + lq]      = (acc0[r] * sr + Abuf[qg * 2048 + row * 64 + lq]) * iv;
      obase[(size_t)row * 64 + 32 + lq] = (acc1[r] * sr + Abuf[qg * 2048 + row * 64 + 32 + lq]) * iv;
    }
  }
}

extern "C" void kernel_launch(void* const* d_in, const int* in_sizes, int n_in,
                              void* d_out, int out_size, void* d_ws, size_t ws_size,
                              hipStream_t stream) {
  const float* Q = (const float*)d_in[0];
  const float* K = (const float*)d_in[1];
  const float* V = (const float*)d_in[2];
  float* O = (float*)d_out;

  unsigned short* Kb = (unsigned short*)d_ws;
  unsigned short* Vt = Kb + (size_t)B_ * S_ * 64;

  prep_kernel<<<192, 256, 0, stream>>>(K, V, Kb, Vt);
  attn_kernel<<<B_ * H_ * (S_ / 64), 256, 0, stream>>>(Q, Kb, Vt, O);
}